// Round 9
// baseline (330.992 us; speedup 1.0000x reference)
//
#include <hip/hip_runtime.h>

// 3-layer GCN + mean pool. bf16 storage / MFMA GEMM / fp32 accumulate.
// R9: fused aggregate+GEMM with 1024-thread blocks — 64 simultaneous
// 16-lane node-gathers per block in ONE pass (R8 serialized 4 passes per
// thread). GEMM phase: 16 waves = 4 row-tiles x 4 t-pairs; A-frags from
// LDS, B-frags from fragment-major WTF (L1-hot), C via LDS transpose.

#define DIN 30
#define HD  128

typedef __attribute__((ext_vector_type(8))) short v8s;
typedef __attribute__((ext_vector_type(4))) float v4f;

static __device__ __forceinline__ unsigned short f2bf(float f) {
  unsigned int u = __float_as_uint(f);
  u += 0x7fffu + ((u >> 16) & 1u);   // RNE
  return (unsigned short)(u >> 16);
}
static __device__ __forceinline__ float bflo(unsigned int u) {
  return __uint_as_float(u << 16);
}
static __device__ __forceinline__ float bfhi(unsigned int u) {
  return __uint_as_float(u & 0xffff0000u);
}

// ---------------- preprocessing ----------------
__global__ void k_degree(const int* __restrict__ dst, int* __restrict__ deg, int E) {
  int e = blockIdx.x * blockDim.x + threadIdx.x;
  if (e < E) atomicAdd(&deg[dst[e]], 1);
}

__global__ void k_dinv(const int* __restrict__ deg, float* __restrict__ dinv, int N) {
  int i = blockIdx.x * blockDim.x + threadIdx.x;
  if (i < N) dinv[i] = rsqrtf((float)(1 + deg[i]));
}

__global__ void k_scan1(const int* __restrict__ deg, int* __restrict__ bsum, int N) {
  __shared__ int s[256];
  int tid = threadIdx.x;
  int base = blockIdx.x * 1024 + tid * 4;
  int t = 0;
#pragma unroll
  for (int j = 0; j < 4; ++j) { int idx = base + j; if (idx < N) t += deg[idx]; }
  s[tid] = t; __syncthreads();
  for (int d = 128; d > 0; d >>= 1) { if (tid < d) s[tid] += s[tid + d]; __syncthreads(); }
  if (tid == 0) bsum[blockIdx.x] = s[0];
}

__global__ void k_scan2(const int* __restrict__ bsum, int* __restrict__ boff, int nb) {
  __shared__ int s[256];
  int tid = threadIdx.x;
  int v = (tid < nb) ? bsum[tid] : 0;
  s[tid] = v; __syncthreads();
  for (int d = 1; d < 256; d <<= 1) {
    int t = (tid >= d) ? s[tid - d] : 0;
    __syncthreads();
    s[tid] += t;
    __syncthreads();
  }
  boff[tid] = s[tid] - v;
}

__global__ void k_scan3(const int* __restrict__ deg, const int* __restrict__ boff,
                        int* __restrict__ rowptr, int* __restrict__ cursor, int N) {
  __shared__ int s[256];
  int tid = threadIdx.x;
  int base = blockIdx.x * 1024 + tid * 4;
  int v[4]; int t = 0;
#pragma unroll
  for (int j = 0; j < 4; ++j) { int idx = base + j; v[j] = (idx < N) ? deg[idx] : 0; t += v[j]; }
  s[tid] = t; __syncthreads();
  for (int d = 1; d < 256; d <<= 1) {
    int u = (tid >= d) ? s[tid - d] : 0;
    __syncthreads();
    s[tid] += u;
    __syncthreads();
  }
  int run = boff[blockIdx.x] + s[tid] - t;
#pragma unroll
  for (int j = 0; j < 4; ++j) {
    int idx = base + j;
    if (idx < N) { rowptr[idx] = run; cursor[idx] = run; }
    run += v[j];
    if (idx == N - 1) rowptr[N] = run;
  }
}

// CSR scatter with fused per-edge weight: ecw[pos] = (src, dinv[src]*dinv[dst])
__global__ void k_scatter(const int* __restrict__ src, const int* __restrict__ dst,
                          const float* __restrict__ dinv,
                          int* __restrict__ cursor, uint2* __restrict__ ecw, int E) {
  int e = blockIdx.x * blockDim.x + threadIdx.x;
  if (e < E) {
    int s = src[e], d = dst[e];
    int pos = atomicAdd(&cursor[d], 1);
    float w = dinv[s] * dinv[d];
    ecw[pos] = make_uint2((unsigned int)s, __float_as_uint(w));
  }
}

// W [K][128] fp32 -> fragment-major WTF bf16 (R7)
__global__ void k_wtf(const float* __restrict__ W, unsigned short* __restrict__ WTF,
                      int Kreal, int KK) {
  int idx = blockIdx.x * blockDim.x + threadIdx.x;
  int total = 8 * KK * 64 * 8;
  if (idx >= total) return;
  int j = idx & 7;
  int c = idx >> 3;
  int l15 = c & 15;
  int quad = (c >> 4) & 3;
  int kk = (c >> 6) % KK;
  int t = c / (64 * KK);
  int k = kk * 32 + quad * 8 + j;
  int n = t * 16 + l15;
  WTF[idx] = (k < Kreal) ? f2bf(W[k * 128 + n]) : (unsigned short)0;
}

// graph segment starts from sorted batch_idx
__global__ void k_bounds(const int* __restrict__ batch, int* __restrict__ gstart,
                         int N, int G) {
  int i = blockIdx.x * blockDim.x + threadIdx.x;
  if (i >= N) return;
  int b = batch[i];
  int prev = (i == 0) ? -1 : batch[i - 1];
  for (int g = prev + 1; g <= b; ++g) gstart[g] = i;
  if (i == N - 1)
    for (int g = b + 1; g <= G; ++g) gstart[g] = N;
}

// ---------------- fused aggregate + MFMA GEMM ----------------
// Block = 64 nodes, 1024 threads. Phase 1: each 16-lane group gathers one
// node (single pass, 64 concurrent gathers/block). Phase 2: 16 waves =
// 4 row-tiles x 4 t-pairs. Phase 3: LDS transpose -> coalesced stores.
template <int K>
__global__ __launch_bounds__(1024, 8) void k_fused(const void* __restrict__ hin,
                                                   const unsigned short* __restrict__ WTF,
                                                   const float* __restrict__ b,
                                                   const int* __restrict__ rowptr,
                                                   const uint2* __restrict__ ecw,
                                                   const float* __restrict__ dinv,
                                                   unsigned short* __restrict__ C, int N) {
  constexpr int KK = K / 32;
  constexpr int KP = (K == 128) ? 136 : 40;   // A row stride (ushorts)
  constexpr int CP = 132;                     // C-transpose stride
  constexpr int SMSZ = (64 * KP > 64 * CP) ? 64 * KP : 64 * CP;
  __shared__ __align__(16) unsigned short sm[SMSZ];

  int tid = threadIdx.x;
  int l16 = tid & 15;
  int nl = tid >> 4;           // 0..63: one node per 16-lane group
  int row0 = blockIdx.x * 64;
  int node = row0 + nl;

  // ---- phase 1: aggregate 64 rows into LDS (bf16), single pass ----
  if (K == 32) {
    const float* xp = (const float*)hin;
    int f = l16 * 2;
    bool valid = (node < N) && (f < DIN);
    float a0 = 0.f, a1 = 0.f;
    if (node < N) {
      float di = dinv[node];
      float wsf = di * di;
      if (valid) {
        float2 v = *(const float2*)(xp + (size_t)node * DIN + f);
        a0 = v.x * wsf; a1 = v.y * wsf;
      }
      int e0 = rowptr[node], e1 = rowptr[node + 1];
      int e = e0;
      for (; e + 2 <= e1; e += 2) {
        uint2 p0 = ecw[e], p1 = ecw[e + 1];
        float w0 = __uint_as_float(p0.y), w1 = __uint_as_float(p1.y);
        if (valid) {
          float2 v0 = *(const float2*)(xp + (size_t)p0.x * DIN + f);
          float2 v1 = *(const float2*)(xp + (size_t)p1.x * DIN + f);
          a0 = fmaf(v0.x, w0, a0); a1 = fmaf(v0.y, w0, a1);
          a0 = fmaf(v1.x, w1, a0); a1 = fmaf(v1.y, w1, a1);
        }
      }
      if (e < e1) {
        uint2 p0 = ecw[e];
        float w0 = __uint_as_float(p0.y);
        if (valid) {
          float2 v0 = *(const float2*)(xp + (size_t)p0.x * DIN + f);
          a0 = fmaf(v0.x, w0, a0); a1 = fmaf(v0.y, w0, a1);
        }
      }
    }
    *(unsigned int*)&sm[nl * KP + l16 * 2] =
        (unsigned int)f2bf(a0) | ((unsigned int)f2bf(a1) << 16);
  } else {
    const uint4* hp = (const uint4*)hin;
    float a0 = 0.f, a1 = 0.f, a2 = 0.f, a3 = 0.f, a4 = 0.f, a5 = 0.f, a6 = 0.f, a7 = 0.f;
    if (node < N) {
      float di = dinv[node];
      float wsf = di * di;
      uint4 u = hp[(size_t)node * 16 + l16];
      a0 = bflo(u.x) * wsf; a1 = bfhi(u.x) * wsf;
      a2 = bflo(u.y) * wsf; a3 = bfhi(u.y) * wsf;
      a4 = bflo(u.z) * wsf; a5 = bfhi(u.z) * wsf;
      a6 = bflo(u.w) * wsf; a7 = bfhi(u.w) * wsf;
      int e0 = rowptr[node], e1 = rowptr[node + 1];
      int e = e0;
      for (; e + 2 <= e1; e += 2) {
        uint2 p0 = ecw[e], p1 = ecw[e + 1];
        uint4 v0 = hp[(size_t)p0.x * 16 + l16];
        uint4 v1 = hp[(size_t)p1.x * 16 + l16];
        float w0 = __uint_as_float(p0.y), w1 = __uint_as_float(p1.y);
        a0 = fmaf(bflo(v0.x), w0, a0); a1 = fmaf(bfhi(v0.x), w0, a1);
        a2 = fmaf(bflo(v0.y), w0, a2); a3 = fmaf(bfhi(v0.y), w0, a3);
        a4 = fmaf(bflo(v0.z), w0, a4); a5 = fmaf(bfhi(v0.z), w0, a5);
        a6 = fmaf(bflo(v0.w), w0, a6); a7 = fmaf(bfhi(v0.w), w0, a7);
        a0 = fmaf(bflo(v1.x), w1, a0); a1 = fmaf(bfhi(v1.x), w1, a1);
        a2 = fmaf(bflo(v1.y), w1, a2); a3 = fmaf(bfhi(v1.y), w1, a3);
        a4 = fmaf(bflo(v1.z), w1, a4); a5 = fmaf(bfhi(v1.z), w1, a5);
        a6 = fmaf(bflo(v1.w), w1, a6); a7 = fmaf(bfhi(v1.w), w1, a7);
      }
      if (e < e1) {
        uint2 p0 = ecw[e];
        uint4 v0 = hp[(size_t)p0.x * 16 + l16];
        float w0 = __uint_as_float(p0.y);
        a0 = fmaf(bflo(v0.x), w0, a0); a1 = fmaf(bfhi(v0.x), w0, a1);
        a2 = fmaf(bflo(v0.y), w0, a2); a3 = fmaf(bfhi(v0.y), w0, a3);
        a4 = fmaf(bflo(v0.z), w0, a4); a5 = fmaf(bfhi(v0.z), w0, a5);
        a6 = fmaf(bflo(v0.w), w0, a6); a7 = fmaf(bfhi(v0.w), w0, a7);
      }
    }
    uint4 o;
    o.x = (unsigned int)f2bf(a0) | ((unsigned int)f2bf(a1) << 16);
    o.y = (unsigned int)f2bf(a2) | ((unsigned int)f2bf(a3) << 16);
    o.z = (unsigned int)f2bf(a4) | ((unsigned int)f2bf(a5) << 16);
    o.w = (unsigned int)f2bf(a6) | ((unsigned int)f2bf(a7) << 16);
    *(uint4*)&sm[nl * KP + l16 * 8] = o;
  }
  __syncthreads();

  // ---- phase 2: A-fragments from LDS; 16 waves = 4 row-tiles x 4 t-pairs ----
  int wv = tid >> 6, lane = tid & 63, quad = lane >> 4, l15 = lane & 15;
  int rt = wv & 3;        // row-tile 0..3
  int tp = wv >> 2;       // t-pair 0..3
  v8s af[KK];
#pragma unroll
  for (int kk = 0; kk < KK; ++kk)
    af[kk] = *(const v8s*)&sm[(rt * 16 + l15) * KP + kk * 32 + quad * 8];
  __syncthreads();   // before reusing sm as C-transpose buffer

#pragma unroll
  for (int tt = 0; tt < 2; ++tt) {
    int t = tp * 2 + tt;
    v4f acc = {0.f, 0.f, 0.f, 0.f};
#pragma unroll
    for (int kk = 0; kk < KK; ++kk) {
      v8s bf = *(const v8s*)(WTF + (size_t)(((t * KK + kk) * 4 + quad) * 16 + l15) * 8);
      acc = __builtin_amdgcn_mfma_f32_16x16x32_bf16(af[kk], bf, acc, 0, 0, 0);
    }
    float bias = b[t * 16 + l15];
#pragma unroll
    for (int i = 0; i < 4; ++i) {
      float o = fmaxf(acc[i] + bias, 0.f);
      sm[(rt * 16 + quad * 4 + i) * CP + t * 16 + l15] = f2bf(o);
    }
  }
  __syncthreads();

  // ---- phase 3: coalesced C store ----
#pragma unroll
  for (int j = 0; j < 2; ++j) {
    int linear = j * 1024 + tid;       // 64 rows x 32 uint2
    int r = linear >> 5, ch = linear & 31;
    uint2 v = *(const uint2*)&sm[r * CP + ch * 4];
    int row = row0 + r;
    if (row < N) ((uint2*)C)[(size_t)row * 32 + ch] = v;
  }
}

// ---------------- mean pool: 1 wave/graph, precomputed bounds ----------------
__global__ void k_pool(const unsigned short* __restrict__ h, const int* __restrict__ gstart,
                       float* __restrict__ out, int G) {
  int g = blockIdx.x * 4 + (threadIdx.x >> 6);
  if (g >= G) return;
  int lane = threadIdx.x & 63;
  int s = gstart[g], e = gstart[g + 1];
  const unsigned int* hp = (const unsigned int*)h;
  float a0 = 0.f, a1 = 0.f;
  for (int n = s; n < e; ++n) {
    unsigned int u = hp[(size_t)n * 64 + lane];
    a0 += bflo(u); a1 += bfhi(u);
  }
  float inv = 1.f / fmaxf((float)(e - s), 1.f);
  ((float2*)out)[(size_t)g * 64 + lane] = make_float2(a0 * inv, a1 * inv);
}

extern "C" void kernel_launch(void* const* d_in, const int* in_sizes, int n_in,
                              void* d_out, int out_size, void* d_ws, size_t ws_size,
                              hipStream_t stream) {
  const float* x  = (const float*)d_in[0];
  const int* ei   = (const int*)d_in[1];
  const int* batch = (const int*)d_in[2];
  const float* W1 = (const float*)d_in[3];
  const float* b1 = (const float*)d_in[4];
  const float* W2 = (const float*)d_in[5];
  const float* b2 = (const float*)d_in[6];
  const float* W3 = (const float*)d_in[7];
  const float* b3 = (const float*)d_in[8];
  float* out = (float*)d_out;
  int N = in_sizes[2];
  int E = in_sizes[1] / 2;
  int G = out_size / HD;
  const int* src = ei;
  const int* dst = ei + E;

  size_t off = 0;
  char* ws = (char*)d_ws;
  auto alloc = [&](size_t bytes) -> void* {
    void* p = ws + off;
    off += (bytes + 255) & ~(size_t)255;
    return p;
  };
  int*   deg    = (int*)alloc((size_t)N * 4);
  float* dinv   = (float*)alloc((size_t)N * 4);
  int*   rowptr = (int*)alloc((size_t)(N + 1) * 4);
  int*   cursor = (int*)alloc((size_t)N * 4);
  uint2* ecw    = (uint2*)alloc((size_t)E * 8);
  int*   bsum   = (int*)alloc(256 * 4);
  int*   boff   = (int*)alloc(256 * 4);
  int*   gstart = (int*)alloc((size_t)(G + 1) * 4);
  unsigned short* hA  = (unsigned short*)alloc((size_t)N * HD * 2);
  unsigned short* hB  = (unsigned short*)alloc((size_t)N * HD * 2);
  unsigned short* W1F = (unsigned short*)alloc(8 * 1 * 64 * 8 * 2);
  unsigned short* W2F = (unsigned short*)alloc(8 * 4 * 64 * 8 * 2);
  unsigned short* W3F = (unsigned short*)alloc(8 * 4 * 64 * 8 * 2);
  (void)ws_size; (void)n_in;

  int nb1024 = (N + 1023) / 1024;
  hipMemsetAsync(deg, 0, (size_t)N * 4, stream);
  k_degree<<<(E + 255) / 256, 256, 0, stream>>>(dst, deg, E);
  k_dinv<<<(N + 255) / 256, 256, 0, stream>>>(deg, dinv, N);
  k_scan1<<<nb1024, 256, 0, stream>>>(deg, bsum, N);
  k_scan2<<<1, 256, 0, stream>>>(bsum, boff, nb1024);
  k_scan3<<<nb1024, 256, 0, stream>>>(deg, boff, rowptr, cursor, N);
  k_scatter<<<(E + 255) / 256, 256, 0, stream>>>(src, dst, dinv, cursor, ecw, E);
  k_wtf<<<16, 256, 0, stream>>>(W1, W1F, DIN, 1);
  k_wtf<<<64, 256, 0, stream>>>(W2, W2F, 128, 4);
  k_wtf<<<64, 256, 0, stream>>>(W3, W3F, 128, 4);
  k_bounds<<<(N + 255) / 256, 256, 0, stream>>>(batch, gstart, N, G);

  int fusedBlocks = (N + 63) / 64;
  k_fused<32><<<fusedBlocks, 1024, 0, stream>>>(x, W1F, b1, rowptr, ecw, dinv, hA, N);
  k_fused<128><<<fusedBlocks, 1024, 0, stream>>>(hA, W2F, b2, rowptr, ecw, dinv, hB, N);
  k_fused<128><<<fusedBlocks, 1024, 0, stream>>>(hB, W3F, b3, rowptr, ecw, dinv, hA, N);
  k_pool<<<(G + 3) / 4, 256, 0, stream>>>(hA, gstart, out, G);
}

// Round 10
// 316.139 us; speedup vs baseline: 1.0470x; 1.0470x over previous
//
#include <hip/hip_runtime.h>

// 3-layer GCN + mean pool. bf16 storage / MFMA GEMM / fp32 accumulate.
// R10: fused128 kernels are at the random-gather BW wall (~2.5 TB/s);
// shrink everything else:
//  - layer 3 fuses the mean-pool: per-segment atomicAdd partials, no C write
//  - x pre-cast to bf16 [N][32]: layer-1 gather rows 120B -> 64B
//  - dinv folded into scan3; single wtf kernel for all three weights

#define DIN 30
#define HD  128

typedef __attribute__((ext_vector_type(8))) short v8s;
typedef __attribute__((ext_vector_type(4))) float v4f;

static __device__ __forceinline__ unsigned short f2bf(float f) {
  unsigned int u = __float_as_uint(f);
  u += 0x7fffu + ((u >> 16) & 1u);   // RNE
  return (unsigned short)(u >> 16);
}
static __device__ __forceinline__ float bf2f(unsigned short s) {
  return __uint_as_float(((unsigned int)s) << 16);
}
static __device__ __forceinline__ float bflo(unsigned int u) {
  return __uint_as_float(u << 16);
}
static __device__ __forceinline__ float bfhi(unsigned int u) {
  return __uint_as_float(u & 0xffff0000u);
}

// ---------------- preprocessing ----------------
__global__ void k_degree(const int* __restrict__ dst, int* __restrict__ deg, int E) {
  int e = blockIdx.x * blockDim.x + threadIdx.x;
  if (e < E) atomicAdd(&deg[dst[e]], 1);
}

__global__ void k_scan1(const int* __restrict__ deg, int* __restrict__ bsum, int N) {
  __shared__ int s[256];
  int tid = threadIdx.x;
  int base = blockIdx.x * 1024 + tid * 4;
  int t = 0;
#pragma unroll
  for (int j = 0; j < 4; ++j) { int idx = base + j; if (idx < N) t += deg[idx]; }
  s[tid] = t; __syncthreads();
  for (int d = 128; d > 0; d >>= 1) { if (tid < d) s[tid] += s[tid + d]; __syncthreads(); }
  if (tid == 0) bsum[blockIdx.x] = s[0];
}

__global__ void k_scan2(const int* __restrict__ bsum, int* __restrict__ boff, int nb) {
  __shared__ int s[256];
  int tid = threadIdx.x;
  int v = (tid < nb) ? bsum[tid] : 0;
  s[tid] = v; __syncthreads();
  for (int d = 1; d < 256; d <<= 1) {
    int t = (tid >= d) ? s[tid - d] : 0;
    __syncthreads();
    s[tid] += t;
    __syncthreads();
  }
  boff[tid] = s[tid] - v;
}

// scan3 + dinv fused (reads deg anyway)
__global__ void k_scan3(const int* __restrict__ deg, const int* __restrict__ boff,
                        int* __restrict__ rowptr, int* __restrict__ cursor,
                        float* __restrict__ dinv, int N) {
  __shared__ int s[256];
  int tid = threadIdx.x;
  int base = blockIdx.x * 1024 + tid * 4;
  int v[4]; int t = 0;
#pragma unroll
  for (int j = 0; j < 4; ++j) { int idx = base + j; v[j] = (idx < N) ? deg[idx] : 0; t += v[j]; }
  s[tid] = t; __syncthreads();
  for (int d = 1; d < 256; d <<= 1) {
    int u = (tid >= d) ? s[tid - d] : 0;
    __syncthreads();
    s[tid] += u;
    __syncthreads();
  }
  int run = boff[blockIdx.x] + s[tid] - t;
#pragma unroll
  for (int j = 0; j < 4; ++j) {
    int idx = base + j;
    if (idx < N) {
      rowptr[idx] = run; cursor[idx] = run;
      dinv[idx] = rsqrtf((float)(1 + v[j]));
    }
    run += v[j];
    if (idx == N - 1) rowptr[N] = run;
  }
}

// CSR scatter with fused per-edge weight: ecw[pos] = (src, dinv[src]*dinv[dst])
__global__ void k_scatter(const int* __restrict__ src, const int* __restrict__ dst,
                          const float* __restrict__ dinv,
                          int* __restrict__ cursor, uint2* __restrict__ ecw, int E) {
  int e = blockIdx.x * blockDim.x + threadIdx.x;
  if (e < E) {
    int s = src[e], d = dst[e];
    int pos = atomicAdd(&cursor[d], 1);
    float w = dinv[s] * dinv[d];
    ecw[pos] = make_uint2((unsigned int)s, __float_as_uint(w));
  }
}

// fragment-major weight pack, one kernel for all three layers
static __device__ __forceinline__ void wtf_one(const float* __restrict__ W,
                                               unsigned short* __restrict__ WTF,
                                               int idx, int Kreal, int KK) {
  int j = idx & 7;
  int c = idx >> 3;
  int l15 = c & 15;
  int quad = (c >> 4) & 3;
  int kk = (c >> 6) % KK;
  int t = c / (64 * KK);
  int k = kk * 32 + quad * 8 + j;
  int n = t * 16 + l15;
  WTF[idx] = (k < Kreal) ? f2bf(W[k * 128 + n]) : (unsigned short)0;
}

__global__ void k_wtf_all(const float* __restrict__ W1, const float* __restrict__ W2,
                          const float* __restrict__ W3,
                          unsigned short* __restrict__ W1F,
                          unsigned short* __restrict__ W2F,
                          unsigned short* __restrict__ W3F) {
  int idx = blockIdx.x * blockDim.x + threadIdx.x;
  if (idx < 4096) wtf_one(W1, W1F, idx, DIN, 1);
  else if (idx < 20480) wtf_one(W2, W2F, idx - 4096, 128, 4);
  else if (idx < 36864) wtf_one(W3, W3F, idx - 20480, 128, 4);
}

// graph segment starts from sorted batch_idx
__global__ void k_bounds(const int* __restrict__ batch, int* __restrict__ gstart,
                         int N, int G) {
  int i = blockIdx.x * blockDim.x + threadIdx.x;
  if (i >= N) return;
  int b = batch[i];
  int prev = (i == 0) ? -1 : batch[i - 1];
  for (int g = prev + 1; g <= b; ++g) gstart[g] = i;
  if (i == N - 1)
    for (int g = b + 1; g <= G; ++g) gstart[g] = N;
}

// x [N][30] fp32 -> xb [N][32] bf16 (features 30,31 zero)
__global__ void k_xcast(const float* __restrict__ x, unsigned short* __restrict__ xb, int N) {
  int idx = blockIdx.x * blockDim.x + threadIdx.x;
  if (idx >= N * 32) return;
  int n = idx >> 5, f = idx & 31;
  float v = (f < DIN) ? x[(size_t)n * DIN + f] : 0.f;
  xb[idx] = f2bf(v);
}

// ---------------- shared phase-1 gather helpers ----------------
// K=32: 1 uint/lane (64B rows); K=128: 1 uint4/lane (256B rows).

// ---------------- fused aggregate + MFMA GEMM (layers 1,2) ----------------
template <int K>
__global__ __launch_bounds__(1024, 8) void k_fused(const unsigned short* __restrict__ hin,
                                                   const unsigned short* __restrict__ WTF,
                                                   const float* __restrict__ b,
                                                   const int* __restrict__ rowptr,
                                                   const uint2* __restrict__ ecw,
                                                   const float* __restrict__ dinv,
                                                   unsigned short* __restrict__ C, int N) {
  constexpr int KK = K / 32;
  constexpr int KP = (K == 128) ? 136 : 40;
  constexpr int CP = 132;
  constexpr int SMSZ = (64 * KP > 64 * CP) ? 64 * KP : 64 * CP;
  __shared__ __align__(16) unsigned short sm[SMSZ];

  int tid = threadIdx.x;
  int l16 = tid & 15;
  int nl = tid >> 4;
  int row0 = blockIdx.x * 64;
  int node = row0 + nl;

  // ---- phase 1: aggregate 64 rows into LDS (bf16), single pass ----
  if (K == 32) {
    const unsigned int* hp = (const unsigned int*)hin;
    float a0 = 0.f, a1 = 0.f;
    if (node < N) {
      float di = dinv[node];
      float wsf = di * di;
      unsigned int u = hp[(size_t)node * 16 + l16];
      a0 = bflo(u) * wsf; a1 = bfhi(u) * wsf;
      int e0 = rowptr[node], e1 = rowptr[node + 1];
      int e = e0;
      for (; e + 2 <= e1; e += 2) {
        uint2 p0 = ecw[e], p1 = ecw[e + 1];
        unsigned int v0 = hp[(size_t)p0.x * 16 + l16];
        unsigned int v1 = hp[(size_t)p1.x * 16 + l16];
        float w0 = __uint_as_float(p0.y), w1 = __uint_as_float(p1.y);
        a0 = fmaf(bflo(v0), w0, a0); a1 = fmaf(bfhi(v0), w0, a1);
        a0 = fmaf(bflo(v1), w1, a0); a1 = fmaf(bfhi(v1), w1, a1);
      }
      if (e < e1) {
        uint2 p0 = ecw[e];
        unsigned int v0 = hp[(size_t)p0.x * 16 + l16];
        float w0 = __uint_as_float(p0.y);
        a0 = fmaf(bflo(v0), w0, a0); a1 = fmaf(bfhi(v0), w0, a1);
      }
    }
    *(unsigned int*)&sm[nl * KP + l16 * 2] =
        (unsigned int)f2bf(a0) | ((unsigned int)f2bf(a1) << 16);
  } else {
    const uint4* hp = (const uint4*)hin;
    float a0 = 0.f, a1 = 0.f, a2 = 0.f, a3 = 0.f, a4 = 0.f, a5 = 0.f, a6 = 0.f, a7 = 0.f;
    if (node < N) {
      float di = dinv[node];
      float wsf = di * di;
      uint4 u = hp[(size_t)node * 16 + l16];
      a0 = bflo(u.x) * wsf; a1 = bfhi(u.x) * wsf;
      a2 = bflo(u.y) * wsf; a3 = bfhi(u.y) * wsf;
      a4 = bflo(u.z) * wsf; a5 = bfhi(u.z) * wsf;
      a6 = bflo(u.w) * wsf; a7 = bfhi(u.w) * wsf;
      int e0 = rowptr[node], e1 = rowptr[node + 1];
      int e = e0;
      for (; e + 2 <= e1; e += 2) {
        uint2 p0 = ecw[e], p1 = ecw[e + 1];
        uint4 v0 = hp[(size_t)p0.x * 16 + l16];
        uint4 v1 = hp[(size_t)p1.x * 16 + l16];
        float w0 = __uint_as_float(p0.y), w1 = __uint_as_float(p1.y);
        a0 = fmaf(bflo(v0.x), w0, a0); a1 = fmaf(bfhi(v0.x), w0, a1);
        a2 = fmaf(bflo(v0.y), w0, a2); a3 = fmaf(bfhi(v0.y), w0, a3);
        a4 = fmaf(bflo(v0.z), w0, a4); a5 = fmaf(bfhi(v0.z), w0, a5);
        a6 = fmaf(bflo(v0.w), w0, a6); a7 = fmaf(bfhi(v0.w), w0, a7);
        a0 = fmaf(bflo(v1.x), w1, a0); a1 = fmaf(bfhi(v1.x), w1, a1);
        a2 = fmaf(bflo(v1.y), w1, a2); a3 = fmaf(bfhi(v1.y), w1, a3);
        a4 = fmaf(bflo(v1.z), w1, a4); a5 = fmaf(bfhi(v1.z), w1, a5);
        a6 = fmaf(bflo(v1.w), w1, a6); a7 = fmaf(bfhi(v1.w), w1, a7);
      }
      if (e < e1) {
        uint2 p0 = ecw[e];
        uint4 v0 = hp[(size_t)p0.x * 16 + l16];
        float w0 = __uint_as_float(p0.y);
        a0 = fmaf(bflo(v0.x), w0, a0); a1 = fmaf(bfhi(v0.x), w0, a1);
        a2 = fmaf(bflo(v0.y), w0, a2); a3 = fmaf(bfhi(v0.y), w0, a3);
        a4 = fmaf(bflo(v0.z), w0, a4); a5 = fmaf(bfhi(v0.z), w0, a5);
        a6 = fmaf(bflo(v0.w), w0, a6); a7 = fmaf(bfhi(v0.w), w0, a7);
      }
    }
    uint4 o;
    o.x = (unsigned int)f2bf(a0) | ((unsigned int)f2bf(a1) << 16);
    o.y = (unsigned int)f2bf(a2) | ((unsigned int)f2bf(a3) << 16);
    o.z = (unsigned int)f2bf(a4) | ((unsigned int)f2bf(a5) << 16);
    o.w = (unsigned int)f2bf(a6) | ((unsigned int)f2bf(a7) << 16);
    *(uint4*)&sm[nl * KP + l16 * 8] = o;
  }
  __syncthreads();

  // ---- phase 2: A-frags from LDS; 16 waves = 4 row-tiles x 4 t-pairs ----
  int wv = tid >> 6, lane = tid & 63, quad = lane >> 4, l15 = lane & 15;
  int rt = wv & 3, tp = wv >> 2;
  v8s af[KK];
#pragma unroll
  for (int kk = 0; kk < KK; ++kk)
    af[kk] = *(const v8s*)&sm[(rt * 16 + l15) * KP + kk * 32 + quad * 8];
  __syncthreads();

#pragma unroll
  for (int tt = 0; tt < 2; ++tt) {
    int t = tp * 2 + tt;
    v4f acc = {0.f, 0.f, 0.f, 0.f};
#pragma unroll
    for (int kk = 0; kk < KK; ++kk) {
      v8s bf = *(const v8s*)(WTF + (size_t)(((t * KK + kk) * 4 + quad) * 16 + l15) * 8);
      acc = __builtin_amdgcn_mfma_f32_16x16x32_bf16(af[kk], bf, acc, 0, 0, 0);
    }
    float bias = b[t * 16 + l15];
#pragma unroll
    for (int i = 0; i < 4; ++i) {
      float o = fmaxf(acc[i] + bias, 0.f);
      sm[(rt * 16 + quad * 4 + i) * CP + t * 16 + l15] = f2bf(o);
    }
  }
  __syncthreads();

  // ---- phase 3: coalesced C store ----
#pragma unroll
  for (int j = 0; j < 2; ++j) {
    int linear = j * 1024 + tid;
    int r = linear >> 5, ch = linear & 31;
    uint2 v = *(const uint2*)&sm[r * CP + ch * 4];
    int row = row0 + r;
    if (row < N) ((uint2*)C)[(size_t)row * 32 + ch] = v;
  }
}

// ---------------- layer 3: fused aggregate + GEMM + pool-atomics ----------------
__global__ __launch_bounds__(1024, 8) void k_fused_pool(const unsigned short* __restrict__ hin,
                                                        const unsigned short* __restrict__ WTF,
                                                        const float* __restrict__ b,
                                                        const int* __restrict__ rowptr,
                                                        const uint2* __restrict__ ecw,
                                                        const float* __restrict__ dinv,
                                                        const int* __restrict__ batch,
                                                        float* __restrict__ out, int N) {
  constexpr int KK = 4, KP = 136, CP = 132;
  constexpr int SMSZ = 64 * KP;   // > 64*CP
  __shared__ __align__(16) unsigned short sm[SMSZ];
  __shared__ int sbatch[64];

  int tid = threadIdx.x;
  int l16 = tid & 15;
  int nl = tid >> 4;
  int row0 = blockIdx.x * 64;
  int node = row0 + nl;

  if (tid < 64) sbatch[tid] = (row0 + tid < N) ? batch[row0 + tid] : -1;

  // ---- phase 1 ----
  {
    const uint4* hp = (const uint4*)hin;
    float a0 = 0.f, a1 = 0.f, a2 = 0.f, a3 = 0.f, a4 = 0.f, a5 = 0.f, a6 = 0.f, a7 = 0.f;
    if (node < N) {
      float di = dinv[node];
      float wsf = di * di;
      uint4 u = hp[(size_t)node * 16 + l16];
      a0 = bflo(u.x) * wsf; a1 = bfhi(u.x) * wsf;
      a2 = bflo(u.y) * wsf; a3 = bfhi(u.y) * wsf;
      a4 = bflo(u.z) * wsf; a5 = bfhi(u.z) * wsf;
      a6 = bflo(u.w) * wsf; a7 = bfhi(u.w) * wsf;
      int e0 = rowptr[node], e1 = rowptr[node + 1];
      int e = e0;
      for (; e + 2 <= e1; e += 2) {
        uint2 p0 = ecw[e], p1 = ecw[e + 1];
        uint4 v0 = hp[(size_t)p0.x * 16 + l16];
        uint4 v1 = hp[(size_t)p1.x * 16 + l16];
        float w0 = __uint_as_float(p0.y), w1 = __uint_as_float(p1.y);
        a0 = fmaf(bflo(v0.x), w0, a0); a1 = fmaf(bfhi(v0.x), w0, a1);
        a2 = fmaf(bflo(v0.y), w0, a2); a3 = fmaf(bfhi(v0.y), w0, a3);
        a4 = fmaf(bflo(v0.z), w0, a4); a5 = fmaf(bfhi(v0.z), w0, a5);
        a6 = fmaf(bflo(v0.w), w0, a6); a7 = fmaf(bfhi(v0.w), w0, a7);
        a0 = fmaf(bflo(v1.x), w1, a0); a1 = fmaf(bfhi(v1.x), w1, a1);
        a2 = fmaf(bflo(v1.y), w1, a2); a3 = fmaf(bfhi(v1.y), w1, a3);
        a4 = fmaf(bflo(v1.z), w1, a4); a5 = fmaf(bfhi(v1.z), w1, a5);
        a6 = fmaf(bflo(v1.w), w1, a6); a7 = fmaf(bfhi(v1.w), w1, a7);
      }
      if (e < e1) {
        uint2 p0 = ecw[e];
        uint4 v0 = hp[(size_t)p0.x * 16 + l16];
        float w0 = __uint_as_float(p0.y);
        a0 = fmaf(bflo(v0.x), w0, a0); a1 = fmaf(bfhi(v0.x), w0, a1);
        a2 = fmaf(bflo(v0.y), w0, a2); a3 = fmaf(bfhi(v0.y), w0, a3);
        a4 = fmaf(bflo(v0.z), w0, a4); a5 = fmaf(bfhi(v0.z), w0, a5);
        a6 = fmaf(bflo(v0.w), w0, a6); a7 = fmaf(bfhi(v0.w), w0, a7);
      }
    }
    uint4 o;
    o.x = (unsigned int)f2bf(a0) | ((unsigned int)f2bf(a1) << 16);
    o.y = (unsigned int)f2bf(a2) | ((unsigned int)f2bf(a3) << 16);
    o.z = (unsigned int)f2bf(a4) | ((unsigned int)f2bf(a5) << 16);
    o.w = (unsigned int)f2bf(a6) | ((unsigned int)f2bf(a7) << 16);
    *(uint4*)&sm[nl * KP + l16 * 8] = o;
  }
  __syncthreads();

  // ---- phase 2 ----
  int wv = tid >> 6, lane = tid & 63, quad = lane >> 4, l15 = lane & 15;
  int rt = wv & 3, tp = wv >> 2;
  v8s af[KK];
#pragma unroll
  for (int kk = 0; kk < KK; ++kk)
    af[kk] = *(const v8s*)&sm[(rt * 16 + l15) * KP + kk * 32 + quad * 8];
  __syncthreads();

#pragma unroll
  for (int tt = 0; tt < 2; ++tt) {
    int t = tp * 2 + tt;
    v4f acc = {0.f, 0.f, 0.f, 0.f};
#pragma unroll
    for (int kk = 0; kk < KK; ++kk) {
      v8s bf = *(const v8s*)(WTF + (size_t)(((t * KK + kk) * 4 + quad) * 16 + l15) * 8);
      acc = __builtin_amdgcn_mfma_f32_16x16x32_bf16(af[kk], bf, acc, 0, 0, 0);
    }
    float bias = b[t * 16 + l15];
#pragma unroll
    for (int i = 0; i < 4; ++i) {
      float o = fmaxf(acc[i] + bias, 0.f);
      sm[(rt * 16 + quad * 4 + i) * CP + t * 16 + l15] = f2bf(o);
    }
  }
  __syncthreads();

  // ---- phase 3: segment-sum the 64 sorted rows, atomicAdd partials ----
  int f = tid & 127;       // feature
  int grp = tid >> 7;      // row group 0..7 (8 rows each)
  float run = 0.f;
  int cur = -1;
#pragma unroll
  for (int j = 0; j < 8; ++j) {
    int r = grp * 8 + j;
    int g = sbatch[r];
    if (g != cur) {
      if (cur >= 0) atomicAdd(&out[(size_t)cur * 128 + f], run);
      run = 0.f; cur = g;
    }
    if (g >= 0) run += bf2f(sm[r * CP + f]);
  }
  if (cur >= 0) atomicAdd(&out[(size_t)cur * 128 + f], run);
}

// divide pooled sums by segment counts
__global__ void k_finalize(float* __restrict__ out, const int* __restrict__ gstart, int G) {
  int idx = blockIdx.x * blockDim.x + threadIdx.x;
  if (idx >= G * 128) return;
  int g = idx >> 7;
  float cnt = (float)(gstart[g + 1] - gstart[g]);
  out[idx] = out[idx] / fmaxf(cnt, 1.f);
}

extern "C" void kernel_launch(void* const* d_in, const int* in_sizes, int n_in,
                              void* d_out, int out_size, void* d_ws, size_t ws_size,
                              hipStream_t stream) {
  const float* x  = (const float*)d_in[0];
  const int* ei   = (const int*)d_in[1];
  const int* batch = (const int*)d_in[2];
  const float* W1 = (const float*)d_in[3];
  const float* b1 = (const float*)d_in[4];
  const float* W2 = (const float*)d_in[5];
  const float* b2 = (const float*)d_in[6];
  const float* W3 = (const float*)d_in[7];
  const float* b3 = (const float*)d_in[8];
  float* out = (float*)d_out;
  int N = in_sizes[2];
  int E = in_sizes[1] / 2;
  int G = out_size / HD;
  const int* src = ei;
  const int* dst = ei + E;

  size_t off = 0;
  char* ws = (char*)d_ws;
  auto alloc = [&](size_t bytes) -> void* {
    void* p = ws + off;
    off += (bytes + 255) & ~(size_t)255;
    return p;
  };
  int*   deg    = (int*)alloc((size_t)N * 4);
  float* dinv   = (float*)alloc((size_t)N * 4);
  int*   rowptr = (int*)alloc((size_t)(N + 1) * 4);
  int*   cursor = (int*)alloc((size_t)N * 4);
  uint2* ecw    = (uint2*)alloc((size_t)E * 8);
  int*   bsum   = (int*)alloc(256 * 4);
  int*   boff   = (int*)alloc(256 * 4);
  int*   gstart = (int*)alloc((size_t)(G + 1) * 4);
  unsigned short* xb  = (unsigned short*)alloc((size_t)N * 32 * 2);
  unsigned short* hA  = (unsigned short*)alloc((size_t)N * HD * 2);
  unsigned short* hB  = (unsigned short*)alloc((size_t)N * HD * 2);
  unsigned short* W1F = (unsigned short*)alloc(4096 * 2);
  unsigned short* W2F = (unsigned short*)alloc(16384 * 2);
  unsigned short* W3F = (unsigned short*)alloc(16384 * 2);
  (void)ws_size; (void)n_in;

  int nb1024 = (N + 1023) / 1024;
  hipMemsetAsync(deg, 0, (size_t)N * 4, stream);
  hipMemsetAsync(out, 0, (size_t)out_size * 4, stream);
  k_degree<<<(E + 255) / 256, 256, 0, stream>>>(dst, deg, E);
  k_scan1<<<nb1024, 256, 0, stream>>>(deg, bsum, N);
  k_scan2<<<1, 256, 0, stream>>>(bsum, boff, nb1024);
  k_scan3<<<nb1024, 256, 0, stream>>>(deg, boff, rowptr, cursor, dinv, N);
  k_scatter<<<(E + 255) / 256, 256, 0, stream>>>(src, dst, dinv, cursor, ecw, E);
  k_wtf_all<<<144, 256, 0, stream>>>(W1, W2, W3, W1F, W2F, W3F);
  k_bounds<<<(N + 255) / 256, 256, 0, stream>>>(batch, gstart, N, G);
  k_xcast<<<(N * 32 + 255) / 256, 256, 0, stream>>>(x, xb, N);

  int fusedBlocks = (N + 63) / 64;
  k_fused<32><<<fusedBlocks, 1024, 0, stream>>>(xb, W1F, b1, rowptr, ecw, dinv, hA, N);
  k_fused<128><<<fusedBlocks, 1024, 0, stream>>>(hA, W2F, b2, rowptr, ecw, dinv, hB, N);
  k_fused_pool<<<fusedBlocks, 1024, 0, stream>>>(hB, W3F, b3, rowptr, ecw, dinv, batch, out, N);
  k_finalize<<<(G * 128 + 255) / 256, 256, 0, stream>>>(out, gstart, G);
}